// Round 4
// baseline (424.663 us; speedup 1.0000x reference)
//
#include <hip/hip_runtime.h>
#include <math.h>

// NoisyTopKRouter: x[65536,1024] fp32 -> gates[65536,8] + aux_loss.
// R7 = R5 (best measured, 378.9us) + finalize folded into the router via a
// last-block ticket; the separate finalize_kernel dispatch + launch gap are
// removed. R6 (512B bursts, 512-thr blocks) was null -> burst granularity
// >=256B is irrelevant; reverting to R5's verified 256-thr structure.
// Evidence ledger: R4 counted-vmcnt -10.4us, R5 channel-stagger -21.6us,
// R6 granularity +0.3us (null). Remaining limiter axes (channels, bursts,
// sync, concurrency 128KB-in-flight/CU vs 22KB needed) are exhausted; the
// router sits near its pattern BW ceiling. This round removes the last
// controllable dispatch; if null, the controllable floor is reached.
// Ticket correctness: each block __threadfence()s after its acc atomics
// (release), increments a device-scope ticket; the winning block
// __threadfence()s (acquire) then plain-loads acc -- no stale copies can
// exist (the winner never cached acc lines before).

#define N_TOKENS   65536
#define EMBED_DIM  1024
#define NE         8
#define BROWS      64                    // rows per block (= one wave of lanes)
#define NBLK       (N_TOKENS / BROWS)    // 1024
#define CHUNK      64                    // k-cols per chunk
#define NCHUNK     (EMBED_DIM / CHUNK)   // 16
#define QSTRIDE    260                   // floats per 4-row quad (256 + 4 pad)
#define NSLOT      64                    // aux accumulator spreading
#define NOISE_EPS  0.2f

#define AS1(p) (const __attribute__((address_space(1))) void*)(p)
#define AS3(p) (__attribute__((address_space(3))) void*)(p)

__global__ __launch_bounds__(256, 4)
void router_kernel(const float* __restrict__ x,
                   const float* __restrict__ eps,
                   const float* __restrict__ wg,
                   const float* __restrict__ wn,
                   float* __restrict__ gates,
                   float* __restrict__ acc,   /* NSLOT*16 floats + 1 ticket */
                   float* __restrict__ out_aux) {
    __shared__ float tile[2][16 * QSTRIDE];   // 33280 B; quad q at q*260 floats

    const int t    = threadIdx.x;
    const int lane = t & 63;
    const int w    = __builtin_amdgcn_readfirstlane(t >> 6);   // wave id 0..3
    const long rowbase = (long)blockIdx.x * BROWS;
    const int  c0 = blockIdx.x & (NCHUNK - 1);   // per-block chunk phase

    // staging map: wave w issues 4 glb_lds, instr i covers quad q=w*4+i
    // (rows 4q..4q+3, cols ca*64..+63). lane -> row 4q+(lane>>4), col (lane&15)*4.
    const int srow = lane >> 4;           // 0..3
    const int scol = (lane & 15) * 4;     // 0..60

    // compute map: lane -> row `lane`; float4 base within tile:
    const int tb = (lane >> 2) * QSTRIDE + (lane & 3) * 64 + w * 16;

    float accg[NE], accn[NE];
#pragma unroll
    for (int e = 0; e < NE; ++e) { accg[e] = 0.f; accn[e] = 0.f; }

    // prologue: stage logical chunks 0,1 (physical c0, c0+1) -> bufs 0,1
#pragma unroll
    for (int cc = 0; cc < 2; ++cc) {
        const int ca = (c0 + cc) & (NCHUNK - 1);
#pragma unroll
        for (int i = 0; i < 4; ++i) {
            const int q = w * 4 + i;
            const float* gp = x + (rowbase + q * 4 + srow) * (long)EMBED_DIM
                              + ca * CHUNK + scol;
            __builtin_amdgcn_global_load_lds(AS1(gp), AS3(&tile[cc][q * QSTRIDE]),
                                             16, 0, 0);
        }
    }

#pragma unroll 1
    for (int c = 0; c < NCHUNK; ++c) {
        const int b  = c & 1;
        const int ca = (c0 + c) & (NCHUNK - 1);   // physical chunk this iter

        // counted wait: logical chunk c's own 4 loads landed; chunk c+1's 4
        // stay in flight across the barrier (T4 — never drain mid-loop).
        if (c == NCHUNK - 1) asm volatile("s_waitcnt vmcnt(0)" ::: "memory");
        else                 asm volatile("s_waitcnt vmcnt(4)" ::: "memory");
        __builtin_amdgcn_s_barrier();          // all waves' chunk-c data in LDS
        asm volatile("" ::: "memory");         // no load hoisted above barrier

        // wave w consumes k-slice [ca*64+16w, +16)
        float4 xv[4];
#pragma unroll
        for (int j = 0; j < 4; ++j)
            xv[j] = *(const float4*)&tile[b][tb + j * 4];
        asm volatile("s_waitcnt lgkmcnt(0)" ::: "memory");  // reads retired
        __builtin_amdgcn_sched_barrier(0);
        __builtin_amdgcn_s_barrier();          // all waves done reading buf b
        asm volatile("" ::: "memory");

        // refill buf b with logical chunk c+2; lands while we FMA
        if (c + 2 < NCHUNK) {
            const int can = (c0 + c + 2) & (NCHUNK - 1);
#pragma unroll
            for (int i = 0; i < 4; ++i) {
                const int q = w * 4 + i;
                const float* gp = x + (rowbase + q * 4 + srow) * (long)EMBED_DIM
                                  + can * CHUNK + scol;
                __builtin_amdgcn_global_load_lds(AS1(gp),
                                                 AS3(&tile[b][q * QSTRIDE]),
                                                 16, 0, 0);
            }
        }

        // weights are wave-uniform (ca is scalar) -> s_load / scalar K$ path
        const float* wgc = wg + ((long)ca * CHUNK + w * 16) * NE;
        const float* wnc = wn + ((long)ca * CHUNK + w * 16) * NE;
#pragma unroll
        for (int j = 0; j < 4; ++j) {
            const float xa[4] = { xv[j].x, xv[j].y, xv[j].z, xv[j].w };
#pragma unroll
            for (int q = 0; q < 4; ++q) {
                const int k = j * 4 + q;
#pragma unroll
                for (int e = 0; e < NE; ++e) {
                    accg[e] = fmaf(xa[q], wgc[k * NE + e], accg[e]);
                    accn[e] = fmaf(xa[q], wnc[k * NE + e], accn[e]);
                }
            }
        }
    }

    // ---- combine 4-way k-split (reuse tile as scratch: 12 KB < 33 KB) ----
    float* part = (float*)tile;
    if (w != 0) {
#pragma unroll
        for (int e = 0; e < NE; ++e) {
            part[((w - 1) * BROWS + lane) * 16 + e]      = accg[e];
            part[((w - 1) * BROWS + lane) * 16 + NE + e] = accn[e];
        }
    }
    __syncthreads();
    if (w != 0) return;

#pragma unroll
    for (int v = 0; v < 3; ++v)
#pragma unroll
        for (int e = 0; e < NE; ++e) {
            accg[e] += part[(v * BROWS + lane) * 16 + e];
            accn[e] += part[(v * BROWS + lane) * 16 + NE + e];
        }

    // ---- fused epilogue (wave 0, one row per lane) — verified in R1/R2 ----
    const long row = rowbase + lane;
    const float* er = eps + row * NE;
    float4 ev0 = *(const float4*)(er);
    float4 ev1 = *(const float4*)(er + 4);
    float epsv[NE] = { ev0.x, ev0.y, ev0.z, ev0.w, ev1.x, ev1.y, ev1.z, ev1.w };

    float noisy[NE];
#pragma unroll
    for (int e = 0; e < NE; ++e) {
        float r = accn[e];
        float sp = fmaxf(r, 0.f) + log1pf(expf(-fabsf(r)));   // stable softplus
        noisy[e] = accg[e] + (sp + NOISE_EPS) * epsv[e];
    }

    int i1 = 0; float v1 = noisy[0];
#pragma unroll
    for (int e = 1; e < NE; ++e) if (noisy[e] > v1) { v1 = noisy[e]; i1 = e; }
    int i2 = -1; float v2 = -INFINITY;
#pragma unroll
    for (int e = 0; e < NE; ++e) if (e != i1 && noisy[e] > v2) { v2 = noisy[e]; i2 = e; }

    float bb = expf(v2 - v1);
    float g2 = bb / (1.f + bb);
    float g1 = 1.f - g2;

    float* gr = gates + row * NE;
    float ov[NE];
#pragma unroll
    for (int e = 0; e < NE; ++e)
        ov[e] = (e == i1) ? g1 : ((e == i2) ? g2 : 0.f);
    *(float4*)(gr)     = make_float4(ov[0], ov[1], ov[2], ov[3]);
    *(float4*)(gr + 4) = make_float4(ov[4], ov[5], ov[6], ov[7]);

    float mx = accg[0];
#pragma unroll
    for (int e = 1; e < NE; ++e) mx = fmaxf(mx, accg[e]);
    float p[NE]; float s = 0.f;
#pragma unroll
    for (int e = 0; e < NE; ++e) { p[e] = expf(accg[e] - mx); s += p[e]; }
    float inv = 1.f / s;

    float vals[16];
#pragma unroll
    for (int e = 0; e < NE; ++e) {
        vals[e]      = p[e] * inv;
        vals[NE + e] = ((i1 == e) ? 1.f : 0.f) + ((i2 == e && g2 > 0.f) ? 1.f : 0.f);
    }
#pragma unroll
    for (int off = 32; off > 0; off >>= 1)
#pragma unroll
        for (int i = 0; i < 16; ++i)
            vals[i] += __shfl_xor(vals[i], off, 64);

    if (lane == 0) {
        float* slot = acc + (blockIdx.x & (NSLOT - 1)) * 16;
#pragma unroll
        for (int i = 0; i < 16; ++i)
            atomicAdd(&slot[i], vals[i]);
    }

    // ---- merged finalize: last block (ticket) computes aux ----
    __threadfence();                              // release our acc adds
    int tk = 0;
    if (lane == 0)
        tk = (int)atomicAdd((unsigned int*)(acc + NSLOT * 16), 1u);
    tk = __shfl(tk, 0, 64);
    if (tk == NBLK - 1) {
        __threadfence();                          // acquire all blocks' adds
        float v = 0.f;
        if (lane < 16) {
#pragma unroll 4
            for (int j = 0; j < NSLOT; ++j) v += acc[j * 16 + lane];
        }
        const float invn = 1.f / (float)N_TOKENS;
        float other = __shfl(v, lane + 8, 64);    // lane<8: s[8+lane]
        if (lane < 8) {
            float term = (v * invn) * (other * invn);
            term += __shfl_xor(term, 1, 64);
            term += __shfl_xor(term, 2, 64);
            term += __shfl_xor(term, 4, 64);
            if (lane == 0) *out_aux = (float)NE * term;
        }
    }
}

extern "C" void kernel_launch(void* const* d_in, const int* in_sizes, int n_in,
                              void* d_out, int out_size, void* d_ws, size_t ws_size,
                              hipStream_t stream) {
    const float* x   = (const float*)d_in[0];
    const float* eps = (const float*)d_in[1];
    const float* wg  = (const float*)d_in[2];
    const float* wn  = (const float*)d_in[3];
    float* out = (float*)d_out;
    float* acc = (float*)d_ws;

    // zero NSLOT*16 aux slots + 1 ticket word
    hipMemsetAsync(d_ws, 0, NSLOT * 16 * sizeof(float) + sizeof(unsigned int),
                   stream);

    router_kernel<<<dim3(NBLK), dim3(256), 0, stream>>>(
        x, eps, wg, wn, out, acc, out + (out_size - 1));
}

// Round 5
// 404.561 us; speedup vs baseline: 1.0497x; 1.0497x over previous
//
#include <hip/hip_runtime.h>
#include <math.h>

// NoisyTopKRouter: x[65536,1024] fp32 -> gates[65536,8] + aux_loss.
// R8 = R5 skeleton with the staging PRIMITIVE swapped:
//   global_load_lds  ->  global_load_dwordx4-to-VGPR (issued one full chunk
//   ahead, T14 issue-early) + ds_write_b128 (write-late, after the buffer's
//   readers barriered).
// Why: R7's counters finally showed the router: 165us at 10% HBM, 10% VALU,
// 0 Mfma, 28% occ -- pure latency/queuing, ~6.4 GB/s/CU delivered. With
// 128KB/CU nominally in flight that implies the global_load_lds path has a
// shallow per-CU outstanding-request queue (~16KB effective). Regular VMEM
// loads use the deep per-wave return queue (vmcnt up to 63) -> this swap is
// the direct test + fix. Also REVERTED R7's last-block ticket (-46us
// regression: 1024 per-block device-scope threadfences = serialized L2
// writebacks); separate finalize_kernel restored.
// Everything else verbatim R5 (best measured 378.9us): QSTRIDE=260 layout,
// chunk-phase stagger (R5, -22us), dual raw barriers, wave-uniform scalar
// weights, 4-way k-split combine, fused epilogue. FMA order bit-identical
// to R5 -> same absmax.

#define N_TOKENS   65536
#define EMBED_DIM  1024
#define NE         8
#define BROWS      64                    // rows per block (= one wave of lanes)
#define CHUNK      64                    // k-cols per chunk
#define NCHUNK     (EMBED_DIM / CHUNK)   // 16
#define QSTRIDE    260                   // floats per 4-row quad (256 + 4 pad)
#define NSLOT      64                    // aux accumulator spreading
#define NOISE_EPS  0.2f

__global__ __launch_bounds__(256, 4)
void router_kernel(const float* __restrict__ x,
                   const float* __restrict__ eps,
                   const float* __restrict__ wg,
                   const float* __restrict__ wn,
                   float* __restrict__ gates,
                   float* __restrict__ acc /* NSLOT x 16 floats */) {
    __shared__ float tile[2][16 * QSTRIDE];   // 33280 B; quad q at q*260 floats

    const int t    = threadIdx.x;
    const int lane = t & 63;
    const int w    = __builtin_amdgcn_readfirstlane(t >> 6);   // wave id 0..3
    const long rowbase = (long)blockIdx.x * BROWS;
    const int  c0 = blockIdx.x & (NCHUNK - 1);   // per-block chunk phase (R5)

    // staging map (same addresses as R5's glb_lds): wave w, instr i -> quad
    // q=w*4+i (rows 4q..4q+3, cols ca*64..+63); lane -> row 4q+(lane>>4),
    // col (lane&15)*4. Dest slot = lane*16B within the quad's 1040B span.
    const int srow = lane >> 4;           // 0..3
    const int scol = (lane & 15) * 4;     // 0..60

    // compute map: lane -> row `lane`; float4 base within tile:
    const int tb = (lane >> 2) * QSTRIDE + (lane & 3) * 64 + w * 16;

    float accg[NE], accn[NE];
#pragma unroll
    for (int e = 0; e < NE; ++e) { accg[e] = 0.f; accn[e] = 0.f; }

    float4 xs[4];   // in-flight staging regs (chunk c+1)

    // prologue: chunk c0 -> regs -> buf0; then issue chunk c0+1 -> regs
    {
        const int ca = c0;
#pragma unroll
        for (int i = 0; i < 4; ++i) {
            const int q = w * 4 + i;
            xs[i] = *(const float4*)(x + (rowbase + q * 4 + srow) * (long)EMBED_DIM
                                     + ca * CHUNK + scol);
        }
        asm volatile("s_waitcnt vmcnt(0)" ::: "memory");
#pragma unroll
        for (int i = 0; i < 4; ++i) {
            const int q = w * 4 + i;
            *(float4*)&tile[0][q * QSTRIDE + lane * 4] = xs[i];
        }
        const int ca1 = (c0 + 1) & (NCHUNK - 1);
#pragma unroll
        for (int i = 0; i < 4; ++i) {
            const int q = w * 4 + i;
            xs[i] = *(const float4*)(x + (rowbase + q * 4 + srow) * (long)EMBED_DIM
                                     + ca1 * CHUNK + scol);
        }
    }

#pragma unroll 1
    for (int c = 0; c < NCHUNK; ++c) {
        const int b  = c & 1;
        const int ca = (c0 + c) & (NCHUNK - 1);   // physical chunk this iter

        if (c + 1 < NCHUNK) {
            // regs hold chunk c+1 (issued a full iteration ago): land + write
            // into buf b^1 (its last readers rendezvoused at barrier #2 of
            // iteration c-1, which we have already passed).
            asm volatile("s_waitcnt vmcnt(0)" ::: "memory");
#pragma unroll
            for (int i = 0; i < 4; ++i) {
                const int q = w * 4 + i;
                *(float4*)&tile[b ^ 1][q * QSTRIDE + lane * 4] = xs[i];
            }
            if (c + 2 < NCHUNK) {   // issue chunk c+2 -> regs (T14 issue-early)
                const int can = (c0 + c + 2) & (NCHUNK - 1);
#pragma unroll
                for (int i = 0; i < 4; ++i) {
                    const int q = w * 4 + i;
                    xs[i] = *(const float4*)(x + (rowbase + q * 4 + srow) *
                                             (long)EMBED_DIM + can * CHUNK + scol);
                }
            }
        }

        asm volatile("s_waitcnt lgkmcnt(0)" ::: "memory");  // my writes committed
        __builtin_amdgcn_s_barrier();          // #1: chunk c complete in buf b
        asm volatile("" ::: "memory");

        // wave w consumes k-slice [ca*64+16w, +16)
        float4 xv[4];
#pragma unroll
        for (int j = 0; j < 4; ++j)
            xv[j] = *(const float4*)&tile[b][tb + j * 4];
        asm volatile("s_waitcnt lgkmcnt(0)" ::: "memory");  // reads retired
        __builtin_amdgcn_sched_barrier(0);
        __builtin_amdgcn_s_barrier();          // #2: all waves done with buf b
        asm volatile("" ::: "memory");

        // weights are wave-uniform (ca is scalar) -> s_load / scalar K$ path
        const float* wgc = wg + ((long)ca * CHUNK + w * 16) * NE;
        const float* wnc = wn + ((long)ca * CHUNK + w * 16) * NE;
#pragma unroll
        for (int j = 0; j < 4; ++j) {
            const float xa[4] = { xv[j].x, xv[j].y, xv[j].z, xv[j].w };
#pragma unroll
            for (int q = 0; q < 4; ++q) {
                const int k = j * 4 + q;
#pragma unroll
                for (int e = 0; e < NE; ++e) {
                    accg[e] = fmaf(xa[q], wgc[k * NE + e], accg[e]);
                    accn[e] = fmaf(xa[q], wnc[k * NE + e], accn[e]);
                }
            }
        }
    }

    // ---- combine 4-way k-split (reuse tile as scratch: 12 KB < 33 KB) ----
    float* part = (float*)tile;
    if (w != 0) {
#pragma unroll
        for (int e = 0; e < NE; ++e) {
            part[((w - 1) * BROWS + lane) * 16 + e]      = accg[e];
            part[((w - 1) * BROWS + lane) * 16 + NE + e] = accn[e];
        }
    }
    __syncthreads();
    if (w != 0) return;

#pragma unroll
    for (int v = 0; v < 3; ++v)
#pragma unroll
        for (int e = 0; e < NE; ++e) {
            accg[e] += part[(v * BROWS + lane) * 16 + e];
            accn[e] += part[(v * BROWS + lane) * 16 + NE + e];
        }

    // ---- fused epilogue (wave 0, one row per lane) — verified in R1/R2 ----
    const long row = rowbase + lane;
    const float* er = eps + row * NE;
    float4 ev0 = *(const float4*)(er);
    float4 ev1 = *(const float4*)(er + 4);
    float epsv[NE] = { ev0.x, ev0.y, ev0.z, ev0.w, ev1.x, ev1.y, ev1.z, ev1.w };

    float noisy[NE];
#pragma unroll
    for (int e = 0; e < NE; ++e) {
        float r = accn[e];
        float sp = fmaxf(r, 0.f) + log1pf(expf(-fabsf(r)));   // stable softplus
        noisy[e] = accg[e] + (sp + NOISE_EPS) * epsv[e];
    }

    int i1 = 0; float v1 = noisy[0];
#pragma unroll
    for (int e = 1; e < NE; ++e) if (noisy[e] > v1) { v1 = noisy[e]; i1 = e; }
    int i2 = -1; float v2 = -INFINITY;
#pragma unroll
    for (int e = 0; e < NE; ++e) if (e != i1 && noisy[e] > v2) { v2 = noisy[e]; i2 = e; }

    float bb = expf(v2 - v1);
    float g2 = bb / (1.f + bb);
    float g1 = 1.f - g2;

    float* gr = gates + row * NE;
    float ov[NE];
#pragma unroll
    for (int e = 0; e < NE; ++e)
        ov[e] = (e == i1) ? g1 : ((e == i2) ? g2 : 0.f);
    *(float4*)(gr)     = make_float4(ov[0], ov[1], ov[2], ov[3]);
    *(float4*)(gr + 4) = make_float4(ov[4], ov[5], ov[6], ov[7]);

    float mx = accg[0];
#pragma unroll
    for (int e = 1; e < NE; ++e) mx = fmaxf(mx, accg[e]);
    float p[NE]; float s = 0.f;
#pragma unroll
    for (int e = 0; e < NE; ++e) { p[e] = expf(accg[e] - mx); s += p[e]; }
    float inv = 1.f / s;

    float vals[16];
#pragma unroll
    for (int e = 0; e < NE; ++e) {
        vals[e]      = p[e] * inv;
        vals[NE + e] = ((i1 == e) ? 1.f : 0.f) + ((i2 == e && g2 > 0.f) ? 1.f : 0.f);
    }
#pragma unroll
    for (int off = 32; off > 0; off >>= 1)
#pragma unroll
        for (int i = 0; i < 16; ++i)
            vals[i] += __shfl_xor(vals[i], off, 64);

    if (lane == 0) {
        float* slot = acc + (blockIdx.x & (NSLOT - 1)) * 16;
#pragma unroll
        for (int i = 0; i < 16; ++i)
            atomicAdd(&slot[i], vals[i]);
    }
}

__global__ void finalize_kernel(const float* __restrict__ acc,
                                float* __restrict__ out_aux) {
    __shared__ float s[16];
    const int t = threadIdx.x;
    if (t < 16) {
        float v = 0.f;
        for (int j = 0; j < NSLOT; ++j) v += acc[j * 16 + t];
        s[t] = v;
    }
    __syncthreads();
    if (t == 0) {
        const float invn = 1.f / (float)N_TOKENS;
        float aux = 0.f;
#pragma unroll
        for (int e = 0; e < NE; ++e)
            aux += (s[e] * invn) * (s[NE + e] * invn);
        *out_aux = (float)NE * aux;
    }
}

extern "C" void kernel_launch(void* const* d_in, const int* in_sizes, int n_in,
                              void* d_out, int out_size, void* d_ws, size_t ws_size,
                              hipStream_t stream) {
    const float* x   = (const float*)d_in[0];
    const float* eps = (const float*)d_in[1];
    const float* wg  = (const float*)d_in[2];
    const float* wn  = (const float*)d_in[3];
    float* out = (float*)d_out;
    float* acc = (float*)d_ws;

    hipMemsetAsync(d_ws, 0, NSLOT * 16 * sizeof(float), stream);

    router_kernel<<<dim3(N_TOKENS / BROWS), dim3(256), 0, stream>>>(
        x, eps, wg, wn, out, acc);
    finalize_kernel<<<dim3(1), dim3(64), 0, stream>>>(acc, out + (out_size - 1));
}